// Round 7
// baseline (311.174 us; speedup 1.0000x reference)
//
#include <hip/hip_runtime.h>
#include <hip/hip_bf16.h>
#include <math.h>

#define Bsz 4
#define CIN 128
#define LL 1024
#define DM 256
#define DI 512
#define DSTATE 64
#define DR 16
#define MM (Bsz * LL)   // 4096
// scan chunking: p1 at NC1=32 (CL1=32), p2 at NC2=16 (CL2=64); comb over 32.
#define NC1 32
#define CL1 32
#define NC2 16
#define CL2 64
#define LOG2E 1.4426950408889634f

typedef short bf16x8 __attribute__((ext_vector_type(8)));
typedef float f32x4 __attribute__((ext_vector_type(4)));

__device__ __forceinline__ float silu_f(float x) {
    return x / (1.0f + __expf(-x));
}

__device__ __forceinline__ unsigned short f2bf(float f) {
    __hip_bfloat16 h = __float2bfloat16(f);
    unsigned short u;
    __builtin_memcpy(&u, &h, sizeof(u));
    return u;
}

__device__ __forceinline__ void cast8(const float4 a, const float4 b, unsigned short* o) {
    o[0] = f2bf(a.x); o[1] = f2bf(a.y); o[2] = f2bf(a.z); o[3] = f2bf(a.w);
    o[4] = f2bf(b.x); o[5] = f2bf(b.y); o[6] = f2bf(b.z); o[7] = f2bf(b.w);
}

// ---------------------------------------------------------------------------
// K1: x_seq[m][o] = sum_c x[b,c,l]*w_proj[o,c];  LayerNorm -> xn (bf16)
// ---------------------------------------------------------------------------
__global__ __launch_bounds__(256) void k_proj_ln(
    const float* __restrict__ x, const float* __restrict__ w_proj,
    const float* __restrict__ ln_g, const float* __restrict__ ln_b,
    float* __restrict__ x_seq, unsigned short* __restrict__ xn_bf)
{
    __shared__ float xv[4][128];
    __shared__ float sSum[4][4], sSum2[4][4];
    __shared__ float sMean[4], sRstd[4];
    const int m0 = blockIdx.x * 4;
    const int b = m0 >> 10;
    const int l0 = m0 & 1023;
    const int tid = threadIdx.x;

    for (int idx = tid; idx < 512; idx += 256) {
        int c = idx >> 2, p = idx & 3;
        xv[p][c] = x[(b * CIN + c) * LL + l0 + p];
    }
    __syncthreads();

    const int o = tid;
    float acc[4] = {0.f, 0.f, 0.f, 0.f};
    const float4* wr = (const float4*)(w_proj + o * CIN);
#pragma unroll 8
    for (int i = 0; i < 32; i++) {
        float4 w4 = wr[i];
#pragma unroll
        for (int p = 0; p < 4; p++) {
            float4 x4 = ((const float4*)xv[p])[i];
            acc[p] = fmaf(w4.x, x4.x, acc[p]);
            acc[p] = fmaf(w4.y, x4.y, acc[p]);
            acc[p] = fmaf(w4.z, x4.z, acc[p]);
            acc[p] = fmaf(w4.w, x4.w, acc[p]);
        }
    }
    const int lane = tid & 63, wid = tid >> 6;
#pragma unroll
    for (int p = 0; p < 4; p++) {
        float v = acc[p], v2 = v * v;
#pragma unroll
        for (int off = 32; off; off >>= 1) {
            v  += __shfl_xor(v, off);
            v2 += __shfl_xor(v2, off);
        }
        if (lane == 0) { sSum[p][wid] = v; sSum2[p][wid] = v2; }
    }
    __syncthreads();
    if (tid < 4) {
        int p = tid;
        float s  = sSum[p][0] + sSum[p][1] + sSum[p][2] + sSum[p][3];
        float s2 = sSum2[p][0] + sSum2[p][1] + sSum2[p][2] + sSum2[p][3];
        float mean = s * (1.0f / 256.0f);
        float var  = s2 * (1.0f / 256.0f) - mean * mean;
        sMean[p] = mean;
        sRstd[p] = rsqrtf(var + 1e-5f);
    }
    __syncthreads();
    const float g = ln_g[o], bb = ln_b[o];
#pragma unroll
    for (int p = 0; p < 4; p++) {
        int m = m0 + p;
        x_seq[m * DM + o] = acc[p];
        xn_bf[m * DM + o] = f2bf((acc[p] - sMean[p]) * sRstd[p] * g + bb);
    }
}

// ---------------------------------------------------------------------------
// in_proj GEMM: xz[m][n] = sum_k xn[m][k] * W[n][k], W fp32 cast in staging.
// M=4096, N=1024, K=256.  128x128 tile, BK=32, 4 waves.
// ---------------------------------------------------------------------------
__global__ __launch_bounds__(256) void k_gemm_in(
    const unsigned short* __restrict__ A, const float* __restrict__ W,
    float* __restrict__ C)
{
    __shared__ unsigned short As[128][40];
    __shared__ unsigned short Ws[128][40];
    const int tid = threadIdx.x;
    const int m0 = blockIdx.x * 128, n0 = blockIdx.y * 128;
    const int wave = tid >> 6, lane = tid & 63;
    const int quad = lane >> 4, tcol = lane & 15;
    const int wm = (wave & 1) << 6, wn = (wave >> 1) << 6;
    f32x4 zero = {0.f, 0.f, 0.f, 0.f};
    f32x4 acc[4][4];
#pragma unroll
    for (int i = 0; i < 4; i++)
#pragma unroll
        for (int j = 0; j < 4; j++) acc[i][j] = zero;

    for (int k0 = 0; k0 < 256; k0 += 32) {
#pragma unroll
        for (int ch = 0; ch < 2; ch++) {
            int id = tid + ch * 256;
            int r = id >> 2, c = (id & 3) * 8;
            *(bf16x8*)&As[r][c] = *(const bf16x8*)&A[(size_t)(m0 + r) * 256 + k0 + c];
            const float4* wp = (const float4*)(W + (size_t)(n0 + r) * 256 + k0 + c);
            unsigned short wv[8];
            cast8(wp[0], wp[1], wv);
            *(bf16x8*)&Ws[r][c] = *(bf16x8*)wv;
        }
        __syncthreads();
        bf16x8 af[4], bfr[4];
#pragma unroll
        for (int i = 0; i < 4; i++)
            af[i] = *(const bf16x8*)&As[wm + i * 16 + tcol][quad * 8];
#pragma unroll
        for (int j = 0; j < 4; j++)
            bfr[j] = *(const bf16x8*)&Ws[wn + j * 16 + tcol][quad * 8];
#pragma unroll
        for (int i = 0; i < 4; i++)
#pragma unroll
            for (int j = 0; j < 4; j++)
                acc[i][j] = __builtin_amdgcn_mfma_f32_16x16x32_bf16(
                    af[i], bfr[j], acc[i][j], 0, 0, 0);
        __syncthreads();
    }
#pragma unroll
    for (int i = 0; i < 4; i++) {
        int m = m0 + wm + i * 16 + quad * 4;
#pragma unroll
        for (int j = 0; j < 4; j++) {
            int n = n0 + wn + j * 16 + tcol;
#pragma unroll
            for (int r = 0; r < 4; r++)
                C[(size_t)(m + r) * 1024 + n] = acc[i][j][r];
        }
    }
}

// ---------------------------------------------------------------------------
// x_proj GEMM with FUSED depthwise conv+SiLU in A-staging.
// A[m][d] = u[m][d] = silu(conv_b[d] + sum_jj xz[m-3+jj][d]*conv_w[d][jj])
// (causal within batch).  Also writes u_buf (fp32) from blockIdx.y==0.
// C = x_dbl (4096 x 144), W = x_proj_w fp32 cast in staging.  K=512.
// ---------------------------------------------------------------------------
__global__ __launch_bounds__(256) void k_gemm_x(
    const float* __restrict__ xz, const float* __restrict__ conv_w,
    const float* __restrict__ conv_b, const float* __restrict__ W,
    float* __restrict__ x_dbl, float* __restrict__ u_buf)
{
    __shared__ unsigned short As[128][40];
    __shared__ unsigned short Ws[128][40];
    const int tid = threadIdx.x;
    const int m0 = blockIdx.x * 128, n0 = blockIdx.y * 128;
    const int wave = tid >> 6, lane = tid & 63;
    const int quad = lane >> 4, tcol = lane & 15;
    const int wm = (wave & 1) << 6, wn = (wave >> 1) << 6;
    const bool write_u = (blockIdx.y == 0);
    f32x4 zero = {0.f, 0.f, 0.f, 0.f};
    f32x4 acc[4][4];
#pragma unroll
    for (int i = 0; i < 4; i++)
#pragma unroll
        for (int j = 0; j < 4; j++) acc[i][j] = zero;

    for (int k0 = 0; k0 < 512; k0 += 32) {
#pragma unroll
        for (int ch = 0; ch < 2; ch++) {
            int id = tid + ch * 256;
            int r = id >> 2, cc = (id & 3) * 8;
            int m = m0 + r;
            int l = m & 1023;
            int d = k0 + cc;
            // conv weights/bias for 8 consecutive d
            float4 cb0 = *(const float4*)(conv_b + d);
            float4 cb1 = *(const float4*)(conv_b + d + 4);
            float a8[8] = {cb0.x, cb0.y, cb0.z, cb0.w, cb1.x, cb1.y, cb1.z, cb1.w};
            float4 w4[8];
#pragma unroll
            for (int q = 0; q < 8; q++) w4[q] = *(const float4*)(conv_w + (d + q) * 4);
#pragma unroll
            for (int jj = 0; jj < 4; jj++) {
                int li = l - 3 + jj;
                if (li >= 0) {
                    const float* row = xz + (size_t)(m - 3 + jj) * 1024 + d;
                    float4 x0 = *(const float4*)row;
                    float4 x1 = *(const float4*)(row + 4);
                    float xv[8] = {x0.x, x0.y, x0.z, x0.w, x1.x, x1.y, x1.z, x1.w};
#pragma unroll
                    for (int q = 0; q < 8; q++)
                        a8[q] = fmaf(xv[q], ((const float*)&w4[q])[jj], a8[q]);
                }
            }
            float us[8];
            unsigned short gv[8];
#pragma unroll
            for (int q = 0; q < 8; q++) { us[q] = silu_f(a8[q]); gv[q] = f2bf(us[q]); }
            *(bf16x8*)&As[r][cc] = *(bf16x8*)gv;
            if (write_u) {
                float* up = u_buf + (size_t)m * DI + d;
                *(float4*)up       = make_float4(us[0], us[1], us[2], us[3]);
                *(float4*)(up + 4) = make_float4(us[4], us[5], us[6], us[7]);
            }
            // W staging (rows >= 144 zero)
            int wrow = n0 + r;
            unsigned short wv[8] = {0, 0, 0, 0, 0, 0, 0, 0};
            if (wrow < 144) {
                const float4* wp = (const float4*)(W + (size_t)wrow * 512 + k0 + cc);
                cast8(wp[0], wp[1], wv);
            }
            *(bf16x8*)&Ws[r][cc] = *(bf16x8*)wv;
        }
        __syncthreads();
        bf16x8 af[4], bfr[4];
#pragma unroll
        for (int i = 0; i < 4; i++)
            af[i] = *(const bf16x8*)&As[wm + i * 16 + tcol][quad * 8];
#pragma unroll
        for (int j = 0; j < 4; j++)
            bfr[j] = *(const bf16x8*)&Ws[wn + j * 16 + tcol][quad * 8];
#pragma unroll
        for (int i = 0; i < 4; i++)
#pragma unroll
            for (int j = 0; j < 4; j++)
                acc[i][j] = __builtin_amdgcn_mfma_f32_16x16x32_bf16(
                    af[i], bfr[j], acc[i][j], 0, 0, 0);
        __syncthreads();
    }
#pragma unroll
    for (int i = 0; i < 4; i++) {
        int m = m0 + wm + i * 16 + quad * 4;
#pragma unroll
        for (int j = 0; j < 4; j++) {
            int n = n0 + wn + j * 16 + tcol;
            if (n < 144) {
#pragma unroll
                for (int r = 0; r < 4; r++)
                    x_dbl[(size_t)(m + r) * 144 + n] = acc[i][j][r];
            }
        }
    }
}

// ---------------------------------------------------------------------------
// delta = softplus(dt @ dt_proj_w^T + dt_proj_b)
// ---------------------------------------------------------------------------
__global__ __launch_bounds__(256) void k_delta(
    const float* __restrict__ x_dbl, const float* __restrict__ dtw,
    const float* __restrict__ dtb, float* __restrict__ delta)
{
    __shared__ float dtv[16];
    const int m = blockIdx.x;
    const int tid = threadIdx.x;
    if (tid < 16) dtv[tid] = x_dbl[(size_t)m * 144 + tid];
    __syncthreads();
#pragma unroll
    for (int nn = 0; nn < 2; nn++) {
        int n = tid + nn * 256;
        float acc = dtb[n];
        const float4* wr = (const float4*)(dtw + n * 16);
#pragma unroll
        for (int r4 = 0; r4 < 4; r4++) {
            float4 w4 = wr[r4];
            float4 d4 = ((const float4*)dtv)[r4];
            acc = fmaf(w4.x, d4.x, acc);
            acc = fmaf(w4.y, d4.y, acc);
            acc = fmaf(w4.z, d4.z, acc);
            acc = fmaf(w4.w, d4.w, acc);
        }
        delta[(size_t)m * DI + n] = (acc > 20.0f) ? acc : log1pf(__expf(acc));
    }
}

// ---------------------------------------------------------------------------
// Scan pass 1: 16-lane groups (4 d per wave), 4 states/lane, NC1=32 chunks.
// 16384 waves -> full occupancy.  decay = exp(A * sum dt)  (exact algebra).
// wid -> b = wid>>12, c = (wid>>7)&31, d0 = (wid&127)*4.
// ---------------------------------------------------------------------------
__global__ __launch_bounds__(256) void k_scan_p1(
    const float* __restrict__ delta, const float* __restrict__ u_buf,
    const float* __restrict__ x_dbl, const float* __restrict__ A_log,
    float* __restrict__ hend, float* __restrict__ decay)
{
    const int wid = (blockIdx.x << 2) + (threadIdx.x >> 6);  // 0..16383
    const int lane = threadIdx.x & 63;
    const int g = lane >> 4, j = lane & 15;
    const int d = ((wid & 127) << 2) + g;
    const int c = (wid >> 7) & 31;
    const int b = wid >> 12;
    float4 Al = *(const float4*)(A_log + d * DSTATE + j * 4);
    const float A0 = -__expf(Al.x) * LOG2E, A1 = -__expf(Al.y) * LOG2E,
                A2 = -__expf(Al.z) * LOG2E, A3 = -__expf(Al.w) * LOG2E;
    const int t0 = c * CL1;
    const float* dl = delta + ((size_t)(b << 10) + t0) * DI + d;
    const float* uu = u_buf + ((size_t)(b << 10) + t0) * DI + d;
    const float* xb = x_dbl + ((size_t)(b << 10) + t0) * 144 + 16 + j * 4;
    float h0 = 0.f, h1 = 0.f, h2 = 0.f, h3 = 0.f;
    float sdt = 0.f;
#pragma unroll 2
    for (int t = 0; t < CL1; t++) {
        float dt_ = dl[t * DI];
        float ut  = uu[t * DI];
        float4 B4 = *(const float4*)(xb + t * 144);
        float du = dt_ * ut;
        sdt += dt_;
        float e0 = exp2f(dt_ * A0), e1 = exp2f(dt_ * A1),
              e2 = exp2f(dt_ * A2), e3 = exp2f(dt_ * A3);
        h0 = fmaf(e0, h0, du * B4.x);
        h1 = fmaf(e1, h1, du * B4.y);
        h2 = fmaf(e2, h2, du * B4.z);
        h3 = fmaf(e3, h3, du * B4.w);
    }
    size_t o = ((size_t)((c << 11) + (b << 9) + d) << 6) + j * 4;
    *(float4*)(hend + o)  = make_float4(h0, h1, h2, h3);
    *(float4*)(decay + o) = make_float4(exp2f(A0 * sdt), exp2f(A1 * sdt),
                                        exp2f(A2 * sdt), exp2f(A3 * sdt));
}

// ---------------------------------------------------------------------------
// Chunk combine over NC1=32 (in place): hend[c] <- true chunk-start state.
// ---------------------------------------------------------------------------
__global__ __launch_bounds__(256) void k_scan_comb(
    float* __restrict__ hend, const float* __restrict__ decay)
{
    const int idx = blockIdx.x * 256 + threadIdx.x;
    float h = 0.f;
#pragma unroll
    for (int c = 0; c < NC1; c++) {
        size_t o = ((size_t)c << 17) + idx;
        float he = hend[o];
        float de = decay[o];
        hend[o] = h;
        h = fmaf(de, h, he);
    }
}

// ---------------------------------------------------------------------------
// Scan pass 2 (R4-proven form): 8-lane groups, 8 states/lane, NC2=16 chunks.
// Reads chunk-start of NC1 chunk 2c.  y = <h,C> + u*D.
// ---------------------------------------------------------------------------
__global__ __launch_bounds__(256) void k_scan_p2(
    const float* __restrict__ delta, const float* __restrict__ u_buf,
    const float* __restrict__ x_dbl, const float* __restrict__ A_log,
    const float* __restrict__ Dp, const float* __restrict__ hstart,
    float* __restrict__ y_buf)
{
    const int wid = (blockIdx.x << 2) + (threadIdx.x >> 6);  // 0..4095
    const int lane = threadIdx.x & 63;
    const int g = lane >> 3, j = lane & 7;
    const int d = ((wid & 63) << 3) + g;
    const int c = (wid >> 6) & 15;
    const int b = wid >> 10;
    float A[8];
    {
        float4 a0 = *(const float4*)(A_log + d * DSTATE + j * 8);
        float4 a1 = *(const float4*)(A_log + d * DSTATE + j * 8 + 4);
        A[0] = -__expf(a0.x); A[1] = -__expf(a0.y);
        A[2] = -__expf(a0.z); A[3] = -__expf(a0.w);
        A[4] = -__expf(a1.x); A[5] = -__expf(a1.y);
        A[6] = -__expf(a1.z); A[7] = -__expf(a1.w);
    }
    const float Dd = Dp[d];
    float h[8];
    {
        // chunk-start of NC1 chunk 2c
        size_t o = ((size_t)((c << 12) + (b << 9) + d) << 6) + j * 8;
        float4 h0 = *(const float4*)(hstart + o);
        float4 h1 = *(const float4*)(hstart + o + 4);
        h[0] = h0.x; h[1] = h0.y; h[2] = h0.z; h[3] = h0.w;
        h[4] = h1.x; h[5] = h1.y; h[6] = h1.z; h[7] = h1.w;
    }
    const int t0 = c * CL2;
    const float* dl = delta + ((size_t)(b << 10) + t0) * DI + d;
    const float* uu = u_buf + ((size_t)(b << 10) + t0) * DI + d;
    const float* xb = x_dbl + ((size_t)(b << 10) + t0) * 144 + 16 + j * 8;
    const float* xc = x_dbl + ((size_t)(b << 10) + t0) * 144 + 80 + j * 8;
    float* yo = y_buf + ((size_t)(b << 10) + t0) * DI + d;
#pragma unroll 2
    for (int t = 0; t < CL2; t++) {
        float dt_ = dl[t * DI];
        float ut  = uu[t * DI];
        float4 B0 = *(const float4*)(xb + t * 144);
        float4 B1 = *(const float4*)(xb + t * 144 + 4);
        float4 C0 = *(const float4*)(xc + t * 144);
        float4 C1 = *(const float4*)(xc + t * 144 + 4);
        float du = dt_ * ut;
        float Bv[8] = {B0.x, B0.y, B0.z, B0.w, B1.x, B1.y, B1.z, B1.w};
        float Cv[8] = {C0.x, C0.y, C0.z, C0.w, C1.x, C1.y, C1.z, C1.w};
        float p = 0.f;
#pragma unroll
        for (int k = 0; k < 8; k++) {
            float e = __expf(dt_ * A[k]);
            h[k] = fmaf(e, h[k], du * Bv[k]);
            p = fmaf(h[k], Cv[k], p);
        }
        p += __shfl_xor(p, 1);
        p += __shfl_xor(p, 2);
        p += __shfl_xor(p, 4);
        if (j == 0) yo[t * DI] = fmaf(ut, Dd, p);
    }
}

// ---------------------------------------------------------------------------
// Out GEMM: A = y*silu(z) in staging (fp32->bf16), W fp32 cast in staging,
// C = A @ W^T + x_seq, NCHW float4 store.  M=4096, N=256, K=512.
// ---------------------------------------------------------------------------
__global__ __launch_bounds__(256) void k_gemm_out(
    const float* __restrict__ Y, const float* __restrict__ XZ,
    const float* __restrict__ W, const float* __restrict__ x_seq,
    float* __restrict__ out)
{
    __shared__ unsigned short As[128][40];
    __shared__ unsigned short Ws[128][40];
    const int tid = threadIdx.x;
    const int m0 = blockIdx.x * 128, n0 = blockIdx.y * 128;
    const int wave = tid >> 6, lane = tid & 63;
    const int quad = lane >> 4, tcol = lane & 15;
    const int wm = (wave & 1) << 6, wn = (wave >> 1) << 6;
    f32x4 zero = {0.f, 0.f, 0.f, 0.f};
    f32x4 acc[4][4];
#pragma unroll
    for (int i = 0; i < 4; i++)
#pragma unroll
        for (int j = 0; j < 4; j++) acc[i][j] = zero;

    for (int k0 = 0; k0 < 512; k0 += 32) {
#pragma unroll
        for (int ch = 0; ch < 2; ch++) {
            int id = tid + ch * 256;
            int r = id >> 2, cc = (id & 3) * 8;
            int m = m0 + r;
            const float4* yp = (const float4*)(Y + (size_t)m * DI + k0 + cc);
            const float4* zp = (const float4*)(XZ + (size_t)m * 1024 + 512 + k0 + cc);
            float4 y0 = yp[0], y1 = yp[1];
            float4 z0 = zp[0], z1 = zp[1];
            unsigned short gv[8];
            gv[0] = f2bf(y0.x * silu_f(z0.x));
            gv[1] = f2bf(y0.y * silu_f(z0.y));
            gv[2] = f2bf(y0.z * silu_f(z0.z));
            gv[3] = f2bf(y0.w * silu_f(z0.w));
            gv[4] = f2bf(y1.x * silu_f(z1.x));
            gv[5] = f2bf(y1.y * silu_f(z1.y));
            gv[6] = f2bf(y1.z * silu_f(z1.z));
            gv[7] = f2bf(y1.w * silu_f(z1.w));
            *(bf16x8*)&As[r][cc] = *(bf16x8*)gv;
            const float4* wp = (const float4*)(W + (size_t)(n0 + r) * 512 + k0 + cc);
            unsigned short wv[8];
            cast8(wp[0], wp[1], wv);
            *(bf16x8*)&Ws[r][cc] = *(bf16x8*)wv;
        }
        __syncthreads();
        bf16x8 af[4], bfr[4];
#pragma unroll
        for (int i = 0; i < 4; i++)
            af[i] = *(const bf16x8*)&As[wm + i * 16 + tcol][quad * 8];
#pragma unroll
        for (int j = 0; j < 4; j++)
            bfr[j] = *(const bf16x8*)&Ws[wn + j * 16 + tcol][quad * 8];
#pragma unroll
        for (int i = 0; i < 4; i++)
#pragma unroll
            for (int j = 0; j < 4; j++)
                acc[i][j] = __builtin_amdgcn_mfma_f32_16x16x32_bf16(
                    af[i], bfr[j], acc[i][j], 0, 0, 0);
        __syncthreads();
    }

    const int b = m0 >> 10;
#pragma unroll
    for (int i = 0; i < 4; i++) {
        int mb = m0 + wm + i * 16 + quad * 4;
        int l0 = mb & 1023;
#pragma unroll
        for (int j = 0; j < 4; j++) {
            int n = n0 + wn + j * 16 + tcol;
            float r0 = acc[i][j][0] + x_seq[(size_t)(mb + 0) * DM + n];
            float r1 = acc[i][j][1] + x_seq[(size_t)(mb + 1) * DM + n];
            float r2 = acc[i][j][2] + x_seq[(size_t)(mb + 2) * DM + n];
            float r3 = acc[i][j][3] + x_seq[(size_t)(mb + 3) * DM + n];
            *(float4*)(out + (size_t)(b * DM + n) * LL + l0) = make_float4(r0, r1, r2, r3);
        }
    }
}

extern "C" void kernel_launch(void* const* d_in, const int* in_sizes, int n_in,
                              void* d_out, int out_size, void* d_ws, size_t ws_size,
                              hipStream_t stream)
{
    const float* x         = (const float*)d_in[0];
    const float* w_proj    = (const float*)d_in[1];
    const float* ln_g      = (const float*)d_in[2];
    const float* ln_b      = (const float*)d_in[3];
    const float* in_proj_w = (const float*)d_in[4];
    const float* conv_w    = (const float*)d_in[5];
    const float* conv_b    = (const float*)d_in[6];
    const float* x_proj_w  = (const float*)d_in[7];
    const float* dt_proj_w = (const float*)d_in[8];
    const float* dt_proj_b = (const float*)d_in[9];
    const float* A_log     = (const float*)d_in[10];
    const float* Dp        = (const float*)d_in[11];
    const float* out_proj_w= (const float*)d_in[12];
    float* out = (float*)d_out;

    const size_t U = 1048576;
    float* ws    = (float*)d_ws;
    float* x_seq = ws;                 // [0,1)U
    float* xz    = ws + 1 * U;         // [1,5)U
    float* u_buf = ws + 5 * U;         // [5,7)U
    float* x_dbl = ws + 7 * U;         // [7,8)U
    float* delta = ws + 8 * U;         // [8,10)U
    float* y_buf = ws + 10 * U;        // [10,12)U
    float* hend  = ws + 12 * U;        // [12,16)U  (NC1*2048*64 = 4M floats)
    float* decay = ws + 16 * U;        // [16,20)U
    unsigned short* xn_bf = (unsigned short*)(ws + 20 * U);  // 1,048,576

    k_proj_ln<<<dim3(MM / 4), dim3(256), 0, stream>>>(x, w_proj, ln_g, ln_b, x_seq, xn_bf);
    k_gemm_in<<<dim3(32, 8), dim3(256), 0, stream>>>(xn_bf, in_proj_w, xz);
    k_gemm_x<<<dim3(32, 2), dim3(256), 0, stream>>>(
        xz, conv_w, conv_b, x_proj_w, x_dbl, u_buf);
    k_delta<<<dim3(MM), dim3(256), 0, stream>>>(x_dbl, dt_proj_w, dt_proj_b, delta);
    k_scan_p1<<<dim3(4096), dim3(256), 0, stream>>>(delta, u_buf, x_dbl, A_log, hend, decay);
    k_scan_comb<<<dim3(512), dim3(256), 0, stream>>>(hend, decay);
    k_scan_p2<<<dim3(1024), dim3(256), 0, stream>>>(
        delta, u_buf, x_dbl, A_log, Dp, hend, y_buf);
    k_gemm_out<<<dim3(32, 2), dim3(256), 0, stream>>>(y_buf, xz, out_proj_w, x_seq, out);
}

// Round 8
// 278.752 us; speedup vs baseline: 1.1163x; 1.1163x over previous
//
#include <hip/hip_runtime.h>
#include <hip/hip_bf16.h>
#include <math.h>

#define Bsz 4
#define CIN 128
#define LL 1024
#define DM 256
#define DI 512
#define DSTATE 64
#define DR 16
#define MM (Bsz * LL)   // 4096
// scan chunking: p1 at NC1=32 (CL1=32), p2 at NC2=16 (CL2=64); comb over 32.
#define NC1 32
#define CL1 32
#define NC2 16
#define CL2 64
#define LOG2E 1.4426950408889634f

typedef short bf16x8 __attribute__((ext_vector_type(8)));
typedef float f32x4 __attribute__((ext_vector_type(4)));

__device__ __forceinline__ float silu_f(float x) {
    return x / (1.0f + __expf(-x));
}

__device__ __forceinline__ unsigned short f2bf(float f) {
    __hip_bfloat16 h = __float2bfloat16(f);
    unsigned short u;
    __builtin_memcpy(&u, &h, sizeof(u));
    return u;
}

__device__ __forceinline__ void cast8(const float4 a, const float4 b, unsigned short* o) {
    o[0] = f2bf(a.x); o[1] = f2bf(a.y); o[2] = f2bf(a.z); o[3] = f2bf(a.w);
    o[4] = f2bf(b.x); o[5] = f2bf(b.y); o[6] = f2bf(b.z); o[7] = f2bf(b.w);
}

// ---------------------------------------------------------------------------
// K1: x_seq[m][o] = sum_c x[b,c,l]*w_proj[o,c];  LayerNorm -> xn (bf16)
// ---------------------------------------------------------------------------
__global__ __launch_bounds__(256) void k_proj_ln(
    const float* __restrict__ x, const float* __restrict__ w_proj,
    const float* __restrict__ ln_g, const float* __restrict__ ln_b,
    float* __restrict__ x_seq, unsigned short* __restrict__ xn_bf)
{
    __shared__ float xv[4][128];
    __shared__ float sSum[4][4], sSum2[4][4];
    __shared__ float sMean[4], sRstd[4];
    const int m0 = blockIdx.x * 4;
    const int b = m0 >> 10;
    const int l0 = m0 & 1023;
    const int tid = threadIdx.x;

    for (int idx = tid; idx < 512; idx += 256) {
        int c = idx >> 2, p = idx & 3;
        xv[p][c] = x[(b * CIN + c) * LL + l0 + p];
    }
    __syncthreads();

    const int o = tid;
    float acc[4] = {0.f, 0.f, 0.f, 0.f};
    const float4* wr = (const float4*)(w_proj + o * CIN);
#pragma unroll 8
    for (int i = 0; i < 32; i++) {
        float4 w4 = wr[i];
#pragma unroll
        for (int p = 0; p < 4; p++) {
            float4 x4 = ((const float4*)xv[p])[i];
            acc[p] = fmaf(w4.x, x4.x, acc[p]);
            acc[p] = fmaf(w4.y, x4.y, acc[p]);
            acc[p] = fmaf(w4.z, x4.z, acc[p]);
            acc[p] = fmaf(w4.w, x4.w, acc[p]);
        }
    }
    const int lane = tid & 63, wid = tid >> 6;
#pragma unroll
    for (int p = 0; p < 4; p++) {
        float v = acc[p], v2 = v * v;
#pragma unroll
        for (int off = 32; off; off >>= 1) {
            v  += __shfl_xor(v, off);
            v2 += __shfl_xor(v2, off);
        }
        if (lane == 0) { sSum[p][wid] = v; sSum2[p][wid] = v2; }
    }
    __syncthreads();
    if (tid < 4) {
        int p = tid;
        float s  = sSum[p][0] + sSum[p][1] + sSum[p][2] + sSum[p][3];
        float s2 = sSum2[p][0] + sSum2[p][1] + sSum2[p][2] + sSum2[p][3];
        float mean = s * (1.0f / 256.0f);
        float var  = s2 * (1.0f / 256.0f) - mean * mean;
        sMean[p] = mean;
        sRstd[p] = rsqrtf(var + 1e-5f);
    }
    __syncthreads();
    const float g = ln_g[o], bb = ln_b[o];
#pragma unroll
    for (int p = 0; p < 4; p++) {
        int m = m0 + p;
        x_seq[m * DM + o] = acc[p];
        xn_bf[m * DM + o] = f2bf((acc[p] - sMean[p]) * sRstd[p] * g + bb);
    }
}

// ---------------------------------------------------------------------------
// in_proj GEMM: xz[m][n] = sum_k xn[m][k] * W[n][k], W fp32 cast in staging.
// M=4096, N=1024, K=256.  128x128 tile, BK=32, 4 waves.
// ---------------------------------------------------------------------------
__global__ __launch_bounds__(256) void k_gemm_in(
    const unsigned short* __restrict__ A, const float* __restrict__ W,
    float* __restrict__ C)
{
    __shared__ unsigned short As[128][40];
    __shared__ unsigned short Ws[128][40];
    const int tid = threadIdx.x;
    const int m0 = blockIdx.x * 128, n0 = blockIdx.y * 128;
    const int wave = tid >> 6, lane = tid & 63;
    const int quad = lane >> 4, tcol = lane & 15;
    const int wm = (wave & 1) << 6, wn = (wave >> 1) << 6;
    f32x4 zero = {0.f, 0.f, 0.f, 0.f};
    f32x4 acc[4][4];
#pragma unroll
    for (int i = 0; i < 4; i++)
#pragma unroll
        for (int j = 0; j < 4; j++) acc[i][j] = zero;

    for (int k0 = 0; k0 < 256; k0 += 32) {
#pragma unroll
        for (int ch = 0; ch < 2; ch++) {
            int id = tid + ch * 256;
            int r = id >> 2, c = (id & 3) * 8;
            *(bf16x8*)&As[r][c] = *(const bf16x8*)&A[(size_t)(m0 + r) * 256 + k0 + c];
            const float4* wp = (const float4*)(W + (size_t)(n0 + r) * 256 + k0 + c);
            unsigned short wv[8];
            cast8(wp[0], wp[1], wv);
            *(bf16x8*)&Ws[r][c] = *(bf16x8*)wv;
        }
        __syncthreads();
        bf16x8 af[4], bfr[4];
#pragma unroll
        for (int i = 0; i < 4; i++)
            af[i] = *(const bf16x8*)&As[wm + i * 16 + tcol][quad * 8];
#pragma unroll
        for (int j = 0; j < 4; j++)
            bfr[j] = *(const bf16x8*)&Ws[wn + j * 16 + tcol][quad * 8];
#pragma unroll
        for (int i = 0; i < 4; i++)
#pragma unroll
            for (int j = 0; j < 4; j++)
                acc[i][j] = __builtin_amdgcn_mfma_f32_16x16x32_bf16(
                    af[i], bfr[j], acc[i][j], 0, 0, 0);
        __syncthreads();
    }
#pragma unroll
    for (int i = 0; i < 4; i++) {
        int m = m0 + wm + i * 16 + quad * 4;
#pragma unroll
        for (int j = 0; j < 4; j++) {
            int n = n0 + wn + j * 16 + tcol;
#pragma unroll
            for (int r = 0; r < 4; r++)
                C[(size_t)(m + r) * 1024 + n] = acc[i][j][r];
        }
    }
}

// ---------------------------------------------------------------------------
// Depthwise causal conv (k=4) + bias + SiLU -> fp32 u (scan) + bf16 u (GEMM)
// ---------------------------------------------------------------------------
__global__ __launch_bounds__(256) void k_conv_silu(
    const float* __restrict__ xz, const float* __restrict__ conv_w,
    const float* __restrict__ conv_b, float* __restrict__ u_buf,
    unsigned short* __restrict__ u_bf)
{
    const int idx = blockIdx.x * 256 + threadIdx.x;
    const int d = idx & 511;
    const int l = (idx >> 9) & 1023;
    const int b = idx >> 19;
    float acc = conv_b[d];
    const float* w = conv_w + d * 4;
#pragma unroll
    for (int j = 0; j < 4; j++) {
        int li = l - 3 + j;
        if (li >= 0)
            acc = fmaf(xz[(size_t)((b << 10) + li) * 1024 + d], w[j], acc);
    }
    float v = silu_f(acc);
    u_buf[idx] = v;
    u_bf[idx] = f2bf(v);
}

// ---------------------------------------------------------------------------
// x_proj GEMM: x_dbl[m][n] = sum_k u[m][k]*W[n][k]; W fp32 cast in staging.
// M=4096, N=144 (guarded), K=512.
// ---------------------------------------------------------------------------
__global__ __launch_bounds__(256) void k_gemm_x(
    const unsigned short* __restrict__ A, const float* __restrict__ W,
    float* __restrict__ C)
{
    __shared__ unsigned short As[128][40];
    __shared__ unsigned short Ws[128][40];
    const int tid = threadIdx.x;
    const int m0 = blockIdx.x * 128, n0 = blockIdx.y * 128;
    const int wave = tid >> 6, lane = tid & 63;
    const int quad = lane >> 4, tcol = lane & 15;
    const int wm = (wave & 1) << 6, wn = (wave >> 1) << 6;
    f32x4 zero = {0.f, 0.f, 0.f, 0.f};
    f32x4 acc[4][4];
#pragma unroll
    for (int i = 0; i < 4; i++)
#pragma unroll
        for (int j = 0; j < 4; j++) acc[i][j] = zero;

    for (int k0 = 0; k0 < 512; k0 += 32) {
#pragma unroll
        for (int ch = 0; ch < 2; ch++) {
            int id = tid + ch * 256;
            int r = id >> 2, c = (id & 3) * 8;
            *(bf16x8*)&As[r][c] = *(const bf16x8*)&A[(size_t)(m0 + r) * 512 + k0 + c];
            int wrow = n0 + r;
            unsigned short wv[8] = {0, 0, 0, 0, 0, 0, 0, 0};
            if (wrow < 144) {
                const float4* wp = (const float4*)(W + (size_t)wrow * 512 + k0 + c);
                cast8(wp[0], wp[1], wv);
            }
            *(bf16x8*)&Ws[r][c] = *(bf16x8*)wv;
        }
        __syncthreads();
        bf16x8 af[4], bfr[4];
#pragma unroll
        for (int i = 0; i < 4; i++)
            af[i] = *(const bf16x8*)&As[wm + i * 16 + tcol][quad * 8];
#pragma unroll
        for (int j = 0; j < 4; j++)
            bfr[j] = *(const bf16x8*)&Ws[wn + j * 16 + tcol][quad * 8];
#pragma unroll
        for (int i = 0; i < 4; i++)
#pragma unroll
            for (int j = 0; j < 4; j++)
                acc[i][j] = __builtin_amdgcn_mfma_f32_16x16x32_bf16(
                    af[i], bfr[j], acc[i][j], 0, 0, 0);
        __syncthreads();
    }
#pragma unroll
    for (int i = 0; i < 4; i++) {
        int m = m0 + wm + i * 16 + quad * 4;
#pragma unroll
        for (int j = 0; j < 4; j++) {
            int n = n0 + wn + j * 16 + tcol;
            if (n < 144) {
#pragma unroll
                for (int r = 0; r < 4; r++)
                    C[(size_t)(m + r) * 144 + n] = acc[i][j][r];
            }
        }
    }
}

// ---------------------------------------------------------------------------
// delta = softplus(dt @ dt_proj_w^T + dt_proj_b)
// ---------------------------------------------------------------------------
__global__ __launch_bounds__(256) void k_delta(
    const float* __restrict__ x_dbl, const float* __restrict__ dtw,
    const float* __restrict__ dtb, float* __restrict__ delta)
{
    __shared__ float dtv[16];
    const int m = blockIdx.x;
    const int tid = threadIdx.x;
    if (tid < 16) dtv[tid] = x_dbl[(size_t)m * 144 + tid];
    __syncthreads();
#pragma unroll
    for (int nn = 0; nn < 2; nn++) {
        int n = tid + nn * 256;
        float acc = dtb[n];
        const float4* wr = (const float4*)(dtw + n * 16);
#pragma unroll
        for (int r4 = 0; r4 < 4; r4++) {
            float4 w4 = wr[r4];
            float4 d4 = ((const float4*)dtv)[r4];
            acc = fmaf(w4.x, d4.x, acc);
            acc = fmaf(w4.y, d4.y, acc);
            acc = fmaf(w4.z, d4.z, acc);
            acc = fmaf(w4.w, d4.w, acc);
        }
        delta[(size_t)m * DI + n] = (acc > 20.0f) ? acc : log1pf(__expf(acc));
    }
}

// ---------------------------------------------------------------------------
// Scan pass 1: 16-lane groups (4 d per wave), 4 states/lane, NC1=32 chunks.
// 16384 waves -> full occupancy.  decay = exp(A * sum dt)  (exact algebra).
// ---------------------------------------------------------------------------
__global__ __launch_bounds__(256) void k_scan_p1(
    const float* __restrict__ delta, const float* __restrict__ u_buf,
    const float* __restrict__ x_dbl, const float* __restrict__ A_log,
    float* __restrict__ hend, float* __restrict__ decay)
{
    const int wid = (blockIdx.x << 2) + (threadIdx.x >> 6);  // 0..16383
    const int lane = threadIdx.x & 63;
    const int g = lane >> 4, j = lane & 15;
    const int d = ((wid & 127) << 2) + g;
    const int c = (wid >> 7) & 31;
    const int b = wid >> 12;
    float4 Al = *(const float4*)(A_log + d * DSTATE + j * 4);
    const float A0 = -__expf(Al.x) * LOG2E, A1 = -__expf(Al.y) * LOG2E,
                A2 = -__expf(Al.z) * LOG2E, A3 = -__expf(Al.w) * LOG2E;
    const int t0 = c * CL1;
    const float* dl = delta + ((size_t)(b << 10) + t0) * DI + d;
    const float* uu = u_buf + ((size_t)(b << 10) + t0) * DI + d;
    const float* xb = x_dbl + ((size_t)(b << 10) + t0) * 144 + 16 + j * 4;
    float h0 = 0.f, h1 = 0.f, h2 = 0.f, h3 = 0.f;
    float sdt = 0.f;
#pragma unroll 2
    for (int t = 0; t < CL1; t++) {
        float dt_ = dl[t * DI];
        float ut  = uu[t * DI];
        float4 B4 = *(const float4*)(xb + t * 144);
        float du = dt_ * ut;
        sdt += dt_;
        float e0 = exp2f(dt_ * A0), e1 = exp2f(dt_ * A1),
              e2 = exp2f(dt_ * A2), e3 = exp2f(dt_ * A3);
        h0 = fmaf(e0, h0, du * B4.x);
        h1 = fmaf(e1, h1, du * B4.y);
        h2 = fmaf(e2, h2, du * B4.z);
        h3 = fmaf(e3, h3, du * B4.w);
    }
    size_t o = ((size_t)((c << 11) + (b << 9) + d) << 6) + j * 4;
    *(float4*)(hend + o)  = make_float4(h0, h1, h2, h3);
    *(float4*)(decay + o) = make_float4(exp2f(A0 * sdt), exp2f(A1 * sdt),
                                        exp2f(A2 * sdt), exp2f(A3 * sdt));
}

// ---------------------------------------------------------------------------
// Chunk combine over NC1=32 (in place): hend[c] <- true chunk-start state.
// ---------------------------------------------------------------------------
__global__ __launch_bounds__(256) void k_scan_comb(
    float* __restrict__ hend, const float* __restrict__ decay)
{
    const int idx = blockIdx.x * 256 + threadIdx.x;
    float h = 0.f;
#pragma unroll
    for (int c = 0; c < NC1; c++) {
        size_t o = ((size_t)c << 17) + idx;
        float he = hend[o];
        float de = decay[o];
        hend[o] = h;
        h = fmaf(de, h, he);
    }
}

// ---------------------------------------------------------------------------
// Scan pass 2 (R4-proven form): 8-lane groups, 8 states/lane, NC2=16 chunks.
// Reads chunk-start of NC1 chunk 2c.  y = <h,C> + u*D.
// ---------------------------------------------------------------------------
__global__ __launch_bounds__(256) void k_scan_p2(
    const float* __restrict__ delta, const float* __restrict__ u_buf,
    const float* __restrict__ x_dbl, const float* __restrict__ A_log,
    const float* __restrict__ Dp, const float* __restrict__ hstart,
    float* __restrict__ y_buf)
{
    const int wid = (blockIdx.x << 2) + (threadIdx.x >> 6);  // 0..4095
    const int lane = threadIdx.x & 63;
    const int g = lane >> 3, j = lane & 7;
    const int d = ((wid & 63) << 3) + g;
    const int c = (wid >> 6) & 15;
    const int b = wid >> 10;
    float A[8];
    {
        float4 a0 = *(const float4*)(A_log + d * DSTATE + j * 8);
        float4 a1 = *(const float4*)(A_log + d * DSTATE + j * 8 + 4);
        A[0] = -__expf(a0.x); A[1] = -__expf(a0.y);
        A[2] = -__expf(a0.z); A[3] = -__expf(a0.w);
        A[4] = -__expf(a1.x); A[5] = -__expf(a1.y);
        A[6] = -__expf(a1.z); A[7] = -__expf(a1.w);
    }
    const float Dd = Dp[d];
    float h[8];
    {
        // chunk-start of NC1 chunk 2c
        size_t o = ((size_t)((c << 12) + (b << 9) + d) << 6) + j * 8;
        float4 h0 = *(const float4*)(hstart + o);
        float4 h1 = *(const float4*)(hstart + o + 4);
        h[0] = h0.x; h[1] = h0.y; h[2] = h0.z; h[3] = h0.w;
        h[4] = h1.x; h[5] = h1.y; h[6] = h1.z; h[7] = h1.w;
    }
    const int t0 = c * CL2;
    const float* dl = delta + ((size_t)(b << 10) + t0) * DI + d;
    const float* uu = u_buf + ((size_t)(b << 10) + t0) * DI + d;
    const float* xb = x_dbl + ((size_t)(b << 10) + t0) * 144 + 16 + j * 8;
    const float* xc = x_dbl + ((size_t)(b << 10) + t0) * 144 + 80 + j * 8;
    float* yo = y_buf + ((size_t)(b << 10) + t0) * DI + d;
#pragma unroll 2
    for (int t = 0; t < CL2; t++) {
        float dt_ = dl[t * DI];
        float ut  = uu[t * DI];
        float4 B0 = *(const float4*)(xb + t * 144);
        float4 B1 = *(const float4*)(xb + t * 144 + 4);
        float4 C0 = *(const float4*)(xc + t * 144);
        float4 C1 = *(const float4*)(xc + t * 144 + 4);
        float du = dt_ * ut;
        float Bv[8] = {B0.x, B0.y, B0.z, B0.w, B1.x, B1.y, B1.z, B1.w};
        float Cv[8] = {C0.x, C0.y, C0.z, C0.w, C1.x, C1.y, C1.z, C1.w};
        float p = 0.f;
#pragma unroll
        for (int k = 0; k < 8; k++) {
            float e = __expf(dt_ * A[k]);
            h[k] = fmaf(e, h[k], du * Bv[k]);
            p = fmaf(h[k], Cv[k], p);
        }
        p += __shfl_xor(p, 1);
        p += __shfl_xor(p, 2);
        p += __shfl_xor(p, 4);
        if (j == 0) yo[t * DI] = fmaf(ut, Dd, p);
    }
}

// ---------------------------------------------------------------------------
// Out GEMM: A = y*silu(z) in staging (fp32->bf16), W fp32 cast in staging,
// C = A @ W^T + x_seq, NCHW float4 store.  M=4096, N=256, K=512.
// ---------------------------------------------------------------------------
__global__ __launch_bounds__(256) void k_gemm_out(
    const float* __restrict__ Y, const float* __restrict__ XZ,
    const float* __restrict__ W, const float* __restrict__ x_seq,
    float* __restrict__ out)
{
    __shared__ unsigned short As[128][40];
    __shared__ unsigned short Ws[128][40];
    const int tid = threadIdx.x;
    const int m0 = blockIdx.x * 128, n0 = blockIdx.y * 128;
    const int wave = tid >> 6, lane = tid & 63;
    const int quad = lane >> 4, tcol = lane & 15;
    const int wm = (wave & 1) << 6, wn = (wave >> 1) << 6;
    f32x4 zero = {0.f, 0.f, 0.f, 0.f};
    f32x4 acc[4][4];
#pragma unroll
    for (int i = 0; i < 4; i++)
#pragma unroll
        for (int j = 0; j < 4; j++) acc[i][j] = zero;

    for (int k0 = 0; k0 < 512; k0 += 32) {
#pragma unroll
        for (int ch = 0; ch < 2; ch++) {
            int id = tid + ch * 256;
            int r = id >> 2, cc = (id & 3) * 8;
            int m = m0 + r;
            const float4* yp = (const float4*)(Y + (size_t)m * DI + k0 + cc);
            const float4* zp = (const float4*)(XZ + (size_t)m * 1024 + 512 + k0 + cc);
            float4 y0 = yp[0], y1 = yp[1];
            float4 z0 = zp[0], z1 = zp[1];
            unsigned short gv[8];
            gv[0] = f2bf(y0.x * silu_f(z0.x));
            gv[1] = f2bf(y0.y * silu_f(z0.y));
            gv[2] = f2bf(y0.z * silu_f(z0.z));
            gv[3] = f2bf(y0.w * silu_f(z0.w));
            gv[4] = f2bf(y1.x * silu_f(z1.x));
            gv[5] = f2bf(y1.y * silu_f(z1.y));
            gv[6] = f2bf(y1.z * silu_f(z1.z));
            gv[7] = f2bf(y1.w * silu_f(z1.w));
            *(bf16x8*)&As[r][cc] = *(bf16x8*)gv;
            const float4* wp = (const float4*)(W + (size_t)(n0 + r) * 512 + k0 + cc);
            unsigned short wv[8];
            cast8(wp[0], wp[1], wv);
            *(bf16x8*)&Ws[r][cc] = *(bf16x8*)wv;
        }
        __syncthreads();
        bf16x8 af[4], bfr[4];
#pragma unroll
        for (int i = 0; i < 4; i++)
            af[i] = *(const bf16x8*)&As[wm + i * 16 + tcol][quad * 8];
#pragma unroll
        for (int j = 0; j < 4; j++)
            bfr[j] = *(const bf16x8*)&Ws[wn + j * 16 + tcol][quad * 8];
#pragma unroll
        for (int i = 0; i < 4; i++)
#pragma unroll
            for (int j = 0; j < 4; j++)
                acc[i][j] = __builtin_amdgcn_mfma_f32_16x16x32_bf16(
                    af[i], bfr[j], acc[i][j], 0, 0, 0);
        __syncthreads();
    }

    const int b = m0 >> 10;
#pragma unroll
    for (int i = 0; i < 4; i++) {
        int mb = m0 + wm + i * 16 + quad * 4;
        int l0 = mb & 1023;
#pragma unroll
        for (int j = 0; j < 4; j++) {
            int n = n0 + wn + j * 16 + tcol;
            float r0 = acc[i][j][0] + x_seq[(size_t)(mb + 0) * DM + n];
            float r1 = acc[i][j][1] + x_seq[(size_t)(mb + 1) * DM + n];
            float r2 = acc[i][j][2] + x_seq[(size_t)(mb + 2) * DM + n];
            float r3 = acc[i][j][3] + x_seq[(size_t)(mb + 3) * DM + n];
            *(float4*)(out + (size_t)(b * DM + n) * LL + l0) = make_float4(r0, r1, r2, r3);
        }
    }
}

extern "C" void kernel_launch(void* const* d_in, const int* in_sizes, int n_in,
                              void* d_out, int out_size, void* d_ws, size_t ws_size,
                              hipStream_t stream)
{
    const float* x         = (const float*)d_in[0];
    const float* w_proj    = (const float*)d_in[1];
    const float* ln_g      = (const float*)d_in[2];
    const float* ln_b      = (const float*)d_in[3];
    const float* in_proj_w = (const float*)d_in[4];
    const float* conv_w    = (const float*)d_in[5];
    const float* conv_b    = (const float*)d_in[6];
    const float* x_proj_w  = (const float*)d_in[7];
    const float* dt_proj_w = (const float*)d_in[8];
    const float* dt_proj_b = (const float*)d_in[9];
    const float* A_log     = (const float*)d_in[10];
    const float* Dp        = (const float*)d_in[11];
    const float* out_proj_w= (const float*)d_in[12];
    float* out = (float*)d_out;

    const size_t U = 1048576;
    float* ws    = (float*)d_ws;
    float* x_seq = ws;                 // [0,1)U
    float* xz    = ws + 1 * U;         // [1,5)U
    float* u_buf = ws + 5 * U;         // [5,7)U
    float* x_dbl = ws + 7 * U;         // [7,8)U
    float* delta = ws + 8 * U;         // [8,10)U
    float* y_buf = ws + 10 * U;        // [10,12)U
    float* hend  = ws + 12 * U;        // [12,16)U  (NC1*2048*64 = 4M floats)
    float* decay = ws + 16 * U;        // [16,20)U
    unsigned short* xn_bf = (unsigned short*)(ws + 20 * U);  // 1,048,576
    unsigned short* u_bf  = xn_bf + 1048576;                 // 2,097,152

    k_proj_ln<<<dim3(MM / 4), dim3(256), 0, stream>>>(x, w_proj, ln_g, ln_b, x_seq, xn_bf);
    k_gemm_in<<<dim3(32, 8), dim3(256), 0, stream>>>(xn_bf, in_proj_w, xz);
    k_conv_silu<<<dim3(Bsz * LL * DI / 256), dim3(256), 0, stream>>>(
        xz, conv_w, conv_b, u_buf, u_bf);
    k_gemm_x<<<dim3(32, 2), dim3(256), 0, stream>>>(u_bf, x_proj_w, x_dbl);
    k_delta<<<dim3(MM), dim3(256), 0, stream>>>(x_dbl, dt_proj_w, dt_proj_b, delta);
    k_scan_p1<<<dim3(4096), dim3(256), 0, stream>>>(delta, u_buf, x_dbl, A_log, hend, decay);
    k_scan_comb<<<dim3(512), dim3(256), 0, stream>>>(hend, decay);
    k_scan_p2<<<dim3(1024), dim3(256), 0, stream>>>(
        delta, u_buf, x_dbl, A_log, Dp, hend, y_buf);
    k_gemm_out<<<dim3(32, 2), dim3(256), 0, stream>>>(y_buf, xz, out_proj_w, x_seq, out);
}

// Round 9
// 260.523 us; speedup vs baseline: 1.1944x; 1.0700x over previous
//
#include <hip/hip_runtime.h>
#include <hip/hip_bf16.h>
#include <math.h>

#define Bsz 4
#define CIN 128
#define LL 1024
#define DM 256
#define DI 512
#define DSTATE 64
#define DR 16
#define MM (Bsz * LL)   // 4096
#define NCH 16          // chunks per (b,d-octet) block in fused scan
#define CLH 64          // chunk length
#define LOG2E 1.4426950408889634f

typedef short bf16x8 __attribute__((ext_vector_type(8)));
typedef float f32x4 __attribute__((ext_vector_type(4)));

__device__ __forceinline__ float silu_f(float x) {
    return x / (1.0f + __expf(-x));
}

__device__ __forceinline__ unsigned short f2bf(float f) {
    __hip_bfloat16 h = __float2bfloat16(f);
    unsigned short u;
    __builtin_memcpy(&u, &h, sizeof(u));
    return u;
}

// ---------------------------------------------------------------------------
// Cast the three GEMM weight matrices to bf16 (one launch) - R4 proven.
// ---------------------------------------------------------------------------
__global__ __launch_bounds__(256) void k_cast_w(
    const float* __restrict__ w_in, const float* __restrict__ w_x,
    const float* __restrict__ w_out, unsigned short* __restrict__ o_in,
    unsigned short* __restrict__ o_x, unsigned short* __restrict__ o_out)
{
    int i = blockIdx.x * 256 + threadIdx.x;
    if (i < 262144)       o_in[i]           = f2bf(w_in[i]);
    else if (i < 335872)  o_x[i - 262144]   = f2bf(w_x[i - 262144]);
    else                  o_out[i - 335872] = f2bf(w_out[i - 335872]);
}

// ---------------------------------------------------------------------------
// K1: x_seq[m][o] = sum_c x[b,c,l]*w_proj[o,c];  LayerNorm -> xn (bf16)
// ---------------------------------------------------------------------------
__global__ __launch_bounds__(256) void k_proj_ln(
    const float* __restrict__ x, const float* __restrict__ w_proj,
    const float* __restrict__ ln_g, const float* __restrict__ ln_b,
    float* __restrict__ x_seq, unsigned short* __restrict__ xn_bf)
{
    __shared__ float xv[4][128];
    __shared__ float sSum[4][4], sSum2[4][4];
    __shared__ float sMean[4], sRstd[4];
    const int m0 = blockIdx.x * 4;
    const int b = m0 >> 10;
    const int l0 = m0 & 1023;
    const int tid = threadIdx.x;

    for (int idx = tid; idx < 512; idx += 256) {
        int c = idx >> 2, p = idx & 3;
        xv[p][c] = x[(b * CIN + c) * LL + l0 + p];
    }
    __syncthreads();

    const int o = tid;
    float acc[4] = {0.f, 0.f, 0.f, 0.f};
    const float4* wr = (const float4*)(w_proj + o * CIN);
#pragma unroll 8
    for (int i = 0; i < 32; i++) {
        float4 w4 = wr[i];
#pragma unroll
        for (int p = 0; p < 4; p++) {
            float4 x4 = ((const float4*)xv[p])[i];
            acc[p] = fmaf(w4.x, x4.x, acc[p]);
            acc[p] = fmaf(w4.y, x4.y, acc[p]);
            acc[p] = fmaf(w4.z, x4.z, acc[p]);
            acc[p] = fmaf(w4.w, x4.w, acc[p]);
        }
    }
    const int lane = tid & 63, wid = tid >> 6;
#pragma unroll
    for (int p = 0; p < 4; p++) {
        float v = acc[p], v2 = v * v;
#pragma unroll
        for (int off = 32; off; off >>= 1) {
            v  += __shfl_xor(v, off);
            v2 += __shfl_xor(v2, off);
        }
        if (lane == 0) { sSum[p][wid] = v; sSum2[p][wid] = v2; }
    }
    __syncthreads();
    if (tid < 4) {
        int p = tid;
        float s  = sSum[p][0] + sSum[p][1] + sSum[p][2] + sSum[p][3];
        float s2 = sSum2[p][0] + sSum2[p][1] + sSum2[p][2] + sSum2[p][3];
        float mean = s * (1.0f / 256.0f);
        float var  = s2 * (1.0f / 256.0f) - mean * mean;
        sMean[p] = mean;
        sRstd[p] = rsqrtf(var + 1e-5f);
    }
    __syncthreads();
    const float g = ln_g[o], bb = ln_b[o];
#pragma unroll
    for (int p = 0; p < 4; p++) {
        int m = m0 + p;
        x_seq[m * DM + o] = acc[p];
        xn_bf[m * DM + o] = f2bf((acc[p] - sMean[p]) * sRstd[p] * g + bb);
    }
}

// ---------------------------------------------------------------------------
// bf16 MFMA GEMM (R4 proven): C[m][n] = sum_k A[m*K+k] * W[n*K+k] (fp32 out)
// 128x128 tile, BK=32, 4 waves, wave = 64x64 quadrant. N guarded.
// ---------------------------------------------------------------------------
__global__ __launch_bounds__(256) void k_gemm_bf(
    const unsigned short* __restrict__ A, const unsigned short* __restrict__ W,
    float* __restrict__ C, int N, int K, int ldc)
{
    __shared__ unsigned short As[128][40];
    __shared__ unsigned short Ws[128][40];
    const int tid = threadIdx.x;
    const int m0 = blockIdx.x * 128, n0 = blockIdx.y * 128;
    const int wave = tid >> 6, lane = tid & 63;
    const int quad = lane >> 4, tcol = lane & 15;
    const int wm = (wave & 1) << 6, wn = (wave >> 1) << 6;
    f32x4 zero = {0.f, 0.f, 0.f, 0.f};
    f32x4 acc[4][4];
#pragma unroll
    for (int i = 0; i < 4; i++)
#pragma unroll
        for (int j = 0; j < 4; j++) acc[i][j] = zero;

    for (int k0 = 0; k0 < K; k0 += 32) {
#pragma unroll
        for (int ch = 0; ch < 2; ch++) {
            int id = tid + ch * 256;
            int r = id >> 2, c = (id & 3) * 8;
            *(bf16x8*)&As[r][c] = *(const bf16x8*)&A[(size_t)(m0 + r) * K + k0 + c];
            int wrow = n0 + r;
            bf16x8 wv = {0, 0, 0, 0, 0, 0, 0, 0};
            if (wrow < N) wv = *(const bf16x8*)&W[(size_t)wrow * K + k0 + c];
            *(bf16x8*)&Ws[r][c] = wv;
        }
        __syncthreads();
        bf16x8 af[4], bfr[4];
#pragma unroll
        for (int i = 0; i < 4; i++)
            af[i] = *(const bf16x8*)&As[wm + i * 16 + tcol][quad * 8];
#pragma unroll
        for (int j = 0; j < 4; j++)
            bfr[j] = *(const bf16x8*)&Ws[wn + j * 16 + tcol][quad * 8];
#pragma unroll
        for (int i = 0; i < 4; i++)
#pragma unroll
            for (int j = 0; j < 4; j++)
                acc[i][j] = __builtin_amdgcn_mfma_f32_16x16x32_bf16(
                    af[i], bfr[j], acc[i][j], 0, 0, 0);
        __syncthreads();
    }
#pragma unroll
    for (int i = 0; i < 4; i++) {
        int m = m0 + wm + i * 16 + quad * 4;
#pragma unroll
        for (int j = 0; j < 4; j++) {
            int n = n0 + wn + j * 16 + tcol;
            if (n < N) {
#pragma unroll
                for (int r = 0; r < 4; r++)
                    C[(size_t)(m + r) * ldc + n] = acc[i][j][r];
            }
        }
    }
}

// ---------------------------------------------------------------------------
// Depthwise causal conv (k=4) + bias + SiLU -> fp32 u (scan) + bf16 u (GEMM)
// ---------------------------------------------------------------------------
__global__ __launch_bounds__(256) void k_conv_silu(
    const float* __restrict__ xz, const float* __restrict__ conv_w,
    const float* __restrict__ conv_b, float* __restrict__ u_buf,
    unsigned short* __restrict__ u_bf)
{
    const int idx = blockIdx.x * 256 + threadIdx.x;
    const int d = idx & 511;
    const int l = (idx >> 9) & 1023;
    const int b = idx >> 19;
    float acc = conv_b[d];
    const float* w = conv_w + d * 4;
#pragma unroll
    for (int j = 0; j < 4; j++) {
        int li = l - 3 + j;
        if (li >= 0)
            acc = fmaf(xz[(size_t)((b << 10) + li) * 1024 + d], w[j], acc);
    }
    float v = silu_f(acc);
    u_buf[idx] = v;
    u_bf[idx] = f2bf(v);
}

// ---------------------------------------------------------------------------
// FUSED selective scan: one block per (b, d-octet). 1024 threads = 16 waves,
// wave c owns chunk c (64 t).  Lanes: 8 groups of 8; group g -> d = d0+g;
// lane j holds states 8j..8j+7.
// Phase 0: delta = softplus(dt @ dtw^T + dtb) -> LDS (computed once).
// Phase 1: local recurrence from h=0 -> hend, decay=exp2(A2*sum dt) in LDS.
// Comb:   16-step serial combine in LDS (512 threads).
// Phase 2: re-run from true chunk-start, y = <h,C> + u*D -> y_buf.
// LDS: 32 + 32 + 32 = 96 KB -> 1 block/CU, 256 blocks = 1 per CU.
// ---------------------------------------------------------------------------
__global__ __launch_bounds__(1024) void k_scan_fused(
    const float* __restrict__ u_buf, const float* __restrict__ x_dbl,
    const float* __restrict__ A_log, const float* __restrict__ dtw,
    const float* __restrict__ dtb, const float* __restrict__ Dp,
    float* __restrict__ y_buf)
{
    __shared__ float sDelta[NCH][CLH][8];   // 32 KB  [chunk][t][d_local]
    __shared__ float sHend[NCH * 512];      // 32 KB  [chunk][g*64 + s]
    __shared__ float sDecay[NCH * 512];     // 32 KB
    const int tid = threadIdx.x;
    const int b = blockIdx.x >> 6;
    const int d0 = (blockIdx.x & 63) << 3;
    const int c = tid >> 6;                  // wave id = chunk
    const int lane = tid & 63;
    const int g = lane >> 3, j = lane & 7;
    const int d = d0 + g;
    const size_t mrow = (size_t)(b << 10) + c * CLH;

    // ---- phase 0: delta for this wave's chunk; lane = t, all 8 local d ----
    {
        const int t = lane;
        const float* dtr = x_dbl + (mrow + t) * 144;
        float4 v0 = *(const float4*)(dtr);
        float4 v1 = *(const float4*)(dtr + 4);
        float4 v2 = *(const float4*)(dtr + 8);
        float4 v3 = *(const float4*)(dtr + 12);
#pragma unroll
        for (int q = 0; q < 8; q++) {
            const float4* wr = (const float4*)(dtw + (size_t)(d0 + q) * 16);
            float4 w0 = wr[0], w1 = wr[1], w2 = wr[2], w3 = wr[3];
            float a = dtb[d0 + q];
            a = fmaf(w0.x, v0.x, a); a = fmaf(w0.y, v0.y, a);
            a = fmaf(w0.z, v0.z, a); a = fmaf(w0.w, v0.w, a);
            a = fmaf(w1.x, v1.x, a); a = fmaf(w1.y, v1.y, a);
            a = fmaf(w1.z, v1.z, a); a = fmaf(w1.w, v1.w, a);
            a = fmaf(w2.x, v2.x, a); a = fmaf(w2.y, v2.y, a);
            a = fmaf(w2.z, v2.z, a); a = fmaf(w2.w, v2.w, a);
            a = fmaf(w3.x, v3.x, a); a = fmaf(w3.y, v3.y, a);
            a = fmaf(w3.z, v3.z, a); a = fmaf(w3.w, v3.w, a);
            sDelta[c][t][q] = (a > 20.0f) ? a : log1pf(__expf(a));
        }
    }
    __syncthreads();

    // A pre-scaled by log2(e)
    float A2[8];
    {
        float4 a0 = *(const float4*)(A_log + d * DSTATE + j * 8);
        float4 a1 = *(const float4*)(A_log + d * DSTATE + j * 8 + 4);
        A2[0] = -__expf(a0.x) * LOG2E; A2[1] = -__expf(a0.y) * LOG2E;
        A2[2] = -__expf(a0.z) * LOG2E; A2[3] = -__expf(a0.w) * LOG2E;
        A2[4] = -__expf(a1.x) * LOG2E; A2[5] = -__expf(a1.y) * LOG2E;
        A2[6] = -__expf(a1.z) * LOG2E; A2[7] = -__expf(a1.w) * LOG2E;
    }
    const float* uu = u_buf + mrow * DI + d;
    const float* xb = x_dbl + mrow * 144 + 16 + j * 8;
    const float* xc = x_dbl + mrow * 144 + 80 + j * 8;

    // ---- phase 1: local recurrence from h=0 ----
    float h[8] = {0.f, 0.f, 0.f, 0.f, 0.f, 0.f, 0.f, 0.f};
    float sdt = 0.f;
#pragma unroll 2
    for (int t = 0; t < CLH; t++) {
        float dt_ = sDelta[c][t][g];
        float ut  = uu[t * DI];
        float4 B0 = *(const float4*)(xb + t * 144);
        float4 B1 = *(const float4*)(xb + t * 144 + 4);
        float du = dt_ * ut;
        sdt += dt_;
        float Bv[8] = {B0.x, B0.y, B0.z, B0.w, B1.x, B1.y, B1.z, B1.w};
#pragma unroll
        for (int k = 0; k < 8; k++) {
            float e = exp2f(dt_ * A2[k]);
            h[k] = fmaf(e, h[k], du * Bv[k]);
        }
    }
    const int sidx = c * 512 + g * 64 + j * 8;
    *(float4*)&sHend[sidx]     = make_float4(h[0], h[1], h[2], h[3]);
    *(float4*)&sHend[sidx + 4] = make_float4(h[4], h[5], h[6], h[7]);
    *(float4*)&sDecay[sidx]     = make_float4(exp2f(A2[0] * sdt), exp2f(A2[1] * sdt),
                                              exp2f(A2[2] * sdt), exp2f(A2[3] * sdt));
    *(float4*)&sDecay[sidx + 4] = make_float4(exp2f(A2[4] * sdt), exp2f(A2[5] * sdt),
                                              exp2f(A2[6] * sdt), exp2f(A2[7] * sdt));
    __syncthreads();

    // ---- combine: hend[c] <- true chunk-start state (512 threads) ----
    if (tid < 512) {
        float hh = 0.f;
#pragma unroll
        for (int cc = 0; cc < NCH; cc++) {
            int o = cc * 512 + tid;
            float he = sHend[o];
            float de = sDecay[o];
            sHend[o] = hh;
            hh = fmaf(de, hh, he);
        }
    }
    __syncthreads();

    // ---- phase 2: re-run from true start, emit y ----
    {
        float4 h0 = *(const float4*)&sHend[sidx];
        float4 h1 = *(const float4*)&sHend[sidx + 4];
        h[0] = h0.x; h[1] = h0.y; h[2] = h0.z; h[3] = h0.w;
        h[4] = h1.x; h[5] = h1.y; h[6] = h1.z; h[7] = h1.w;
    }
    const float Dd = Dp[d];
    float* yo = y_buf + mrow * DI + d;
#pragma unroll 2
    for (int t = 0; t < CLH; t++) {
        float dt_ = sDelta[c][t][g];
        float ut  = uu[t * DI];
        float4 B0 = *(const float4*)(xb + t * 144);
        float4 B1 = *(const float4*)(xb + t * 144 + 4);
        float4 C0 = *(const float4*)(xc + t * 144);
        float4 C1 = *(const float4*)(xc + t * 144 + 4);
        float du = dt_ * ut;
        float Bv[8] = {B0.x, B0.y, B0.z, B0.w, B1.x, B1.y, B1.z, B1.w};
        float Cv[8] = {C0.x, C0.y, C0.z, C0.w, C1.x, C1.y, C1.z, C1.w};
        float p = 0.f;
#pragma unroll
        for (int k = 0; k < 8; k++) {
            float e = exp2f(dt_ * A2[k]);
            h[k] = fmaf(e, h[k], du * Bv[k]);
            p = fmaf(h[k], Cv[k], p);
        }
        p += __shfl_xor(p, 1);
        p += __shfl_xor(p, 2);
        p += __shfl_xor(p, 4);
        if (j == 0) yo[t * DI] = fmaf(ut, Dd, p);
    }
}

// ---------------------------------------------------------------------------
// Out GEMM (bf16 MFMA): A = y*silu(z) in staging (fp32->bf16),
// C = A @ out_proj_w^T + x_seq, NCHW float4 store.  M=4096, N=256, K=512.
// ---------------------------------------------------------------------------
__global__ __launch_bounds__(256) void k_gemm_out_bf(
    const float* __restrict__ Y, const float* __restrict__ XZ,
    const unsigned short* __restrict__ W, const float* __restrict__ x_seq,
    float* __restrict__ out)
{
    __shared__ unsigned short As[128][40];
    __shared__ unsigned short Ws[128][40];
    const int tid = threadIdx.x;
    const int m0 = blockIdx.x * 128, n0 = blockIdx.y * 128;
    const int wave = tid >> 6, lane = tid & 63;
    const int quad = lane >> 4, tcol = lane & 15;
    const int wm = (wave & 1) << 6, wn = (wave >> 1) << 6;
    f32x4 zero = {0.f, 0.f, 0.f, 0.f};
    f32x4 acc[4][4];
#pragma unroll
    for (int i = 0; i < 4; i++)
#pragma unroll
        for (int j = 0; j < 4; j++) acc[i][j] = zero;

    for (int k0 = 0; k0 < 512; k0 += 32) {
#pragma unroll
        for (int ch = 0; ch < 2; ch++) {
            int id = tid + ch * 256;
            int r = id >> 2, cc = (id & 3) * 8;
            int m = m0 + r;
            const float4* yp = (const float4*)(Y + (size_t)m * DI + k0 + cc);
            const float4* zp = (const float4*)(XZ + (size_t)m * 1024 + 512 + k0 + cc);
            float4 y0 = yp[0], y1 = yp[1];
            float4 z0 = zp[0], z1 = zp[1];
            unsigned short gv[8];
            gv[0] = f2bf(y0.x * silu_f(z0.x));
            gv[1] = f2bf(y0.y * silu_f(z0.y));
            gv[2] = f2bf(y0.z * silu_f(z0.z));
            gv[3] = f2bf(y0.w * silu_f(z0.w));
            gv[4] = f2bf(y1.x * silu_f(z1.x));
            gv[5] = f2bf(y1.y * silu_f(z1.y));
            gv[6] = f2bf(y1.z * silu_f(z1.z));
            gv[7] = f2bf(y1.w * silu_f(z1.w));
            *(bf16x8*)&As[r][cc] = *(bf16x8*)gv;
            *(bf16x8*)&Ws[r][cc] = *(const bf16x8*)&W[(size_t)(n0 + r) * 512 + k0 + cc];
        }
        __syncthreads();
        bf16x8 af[4], bfr[4];
#pragma unroll
        for (int i = 0; i < 4; i++)
            af[i] = *(const bf16x8*)&As[wm + i * 16 + tcol][quad * 8];
#pragma unroll
        for (int j = 0; j < 4; j++)
            bfr[j] = *(const bf16x8*)&Ws[wn + j * 16 + tcol][quad * 8];
#pragma unroll
        for (int i = 0; i < 4; i++)
#pragma unroll
            for (int j = 0; j < 4; j++)
                acc[i][j] = __builtin_amdgcn_mfma_f32_16x16x32_bf16(
                    af[i], bfr[j], acc[i][j], 0, 0, 0);
        __syncthreads();
    }

    const int b = m0 >> 10;
#pragma unroll
    for (int i = 0; i < 4; i++) {
        int mb = m0 + wm + i * 16 + quad * 4;
        int l0 = mb & 1023;
#pragma unroll
        for (int j = 0; j < 4; j++) {
            int n = n0 + wn + j * 16 + tcol;
            float r0 = acc[i][j][0] + x_seq[(size_t)(mb + 0) * DM + n];
            float r1 = acc[i][j][1] + x_seq[(size_t)(mb + 1) * DM + n];
            float r2 = acc[i][j][2] + x_seq[(size_t)(mb + 2) * DM + n];
            float r3 = acc[i][j][3] + x_seq[(size_t)(mb + 3) * DM + n];
            *(float4*)(out + (size_t)(b * DM + n) * LL + l0) = make_float4(r0, r1, r2, r3);
        }
    }
}

extern "C" void kernel_launch(void* const* d_in, const int* in_sizes, int n_in,
                              void* d_out, int out_size, void* d_ws, size_t ws_size,
                              hipStream_t stream)
{
    const float* x         = (const float*)d_in[0];
    const float* w_proj    = (const float*)d_in[1];
    const float* ln_g      = (const float*)d_in[2];
    const float* ln_b      = (const float*)d_in[3];
    const float* in_proj_w = (const float*)d_in[4];
    const float* conv_w    = (const float*)d_in[5];
    const float* conv_b    = (const float*)d_in[6];
    const float* x_proj_w  = (const float*)d_in[7];
    const float* dt_proj_w = (const float*)d_in[8];
    const float* dt_proj_b = (const float*)d_in[9];
    const float* A_log     = (const float*)d_in[10];
    const float* Dp        = (const float*)d_in[11];
    const float* out_proj_w= (const float*)d_in[12];
    float* out = (float*)d_out;

    const size_t U = 1048576;
    float* ws    = (float*)d_ws;
    float* x_seq = ws;                 // [0,1)U
    float* xz    = ws + 1 * U;         // [1,5)U
    float* u_buf = ws + 5 * U;         // [5,7)U
    float* x_dbl = ws + 7 * U;         // [7,8)U
    float* y_buf = ws + 8 * U;         // [8,10)U
    unsigned short* bz      = (unsigned short*)(ws + 10 * U);
    unsigned short* xn_bf   = bz;                 // 1,048,576
    unsigned short* u_bf    = bz + 1048576;       // 2,097,152
    unsigned short* w_in_bf = bz + 3145728;       // 262,144
    unsigned short* w_x_bf  = bz + 3407872;       //  73,728
    unsigned short* w_out_bf= bz + 3481600;       // 131,072

    k_cast_w<<<dim3(1824), dim3(256), 0, stream>>>(
        in_proj_w, x_proj_w, out_proj_w, w_in_bf, w_x_bf, w_out_bf);
    k_proj_ln<<<dim3(MM / 4), dim3(256), 0, stream>>>(x, w_proj, ln_g, ln_b, x_seq, xn_bf);
    k_gemm_bf<<<dim3(32, 8), dim3(256), 0, stream>>>(xn_bf, w_in_bf, xz, 1024, 256, 1024);
    k_conv_silu<<<dim3(Bsz * LL * DI / 256), dim3(256), 0, stream>>>(
        xz, conv_w, conv_b, u_buf, u_bf);
    k_gemm_bf<<<dim3(32, 2), dim3(256), 0, stream>>>(u_bf, w_x_bf, x_dbl, 144, 512, 144);
    k_scan_fused<<<dim3(256), dim3(1024), 0, stream>>>(
        u_buf, x_dbl, A_log, dt_proj_w, dt_proj_b, Dp, y_buf);
    k_gemm_out_bf<<<dim3(32, 2), dim3(256), 0, stream>>>(y_buf, xz, w_out_bf, x_seq, out);
}